// Round 1
// baseline (13462.628 us; speedup 1.0000x reference)
//
#include <hip/hip_runtime.h>
#include <stdint.h>

#define ST_CENTER   1
#define ST_ABSORBED 2

static __device__ __forceinline__ uint32_t f2key(float f) {
    uint32_t u = __float_as_uint(f);
    return (u & 0x80000000u) ? ~u : (u | 0x80000000u);
}

// ---------------- init ----------------
__global__ void k_init(const float* __restrict__ hier,
                       unsigned long long* __restrict__ key,
                       unsigned long long* __restrict__ best,
                       int* __restrict__ pred,
                       int* __restrict__ resolved,
                       int* __restrict__ counters,
                       int* __restrict__ sel_out,
                       int V) {
    int v = blockIdx.x * blockDim.x + threadIdx.x;
    if (v < 64) counters[v] = 0;
    if (v >= V) return;
    key[v]      = ((unsigned long long)f2key(hier[v]) << 32) | (unsigned long long)(~(uint32_t)v);
    best[v]     = 0ull;
    pred[v]     = 0;
    resolved[v] = 0;
    sel_out[v]  = -1;
}

// ---------------- build in-degree of "absorption" DAG ----------------
__global__ void k_build(const int* __restrict__ neighs,
                        const unsigned long long* __restrict__ key,
                        int* __restrict__ pred,
                        long E, int K, int kshift) {
    long e = (long)blockIdx.x * blockDim.x + threadIdx.x;
    if (e >= E) return;
    int w = neighs[e];
    if (w < 0) return;
    int u = (kshift >= 0) ? (int)(e >> kshift) : (int)(e / K);
    unsigned long long ku = key[u], kw = key[w];
    if (ku > kw) atomicAdd(&pred[w], 1);   // u is a higher-priority pred of w
}

// ---------------- seed: no higher-priority pred => center ----------------
__global__ void k_seed(const int* __restrict__ pred, int* __restrict__ resolved, int V) {
    int v = blockIdx.x * blockDim.x + threadIdx.x;
    if (v >= V) return;
    if (pred[v] == 0) resolved[v] = ST_CENTER;
}

// ---------------- propagation: static ownership worklist ----------------
__global__ __launch_bounds__(256, 2)
void k_propagate(const int* __restrict__ neighs,
                 const unsigned long long* __restrict__ key,
                 unsigned long long* __restrict__ best,
                 int* __restrict__ pred,
                 int* __restrict__ resolved,
                 int V, int K, int T) {
    int t = blockIdx.x * blockDim.x + threadIdx.x;
    int own[8];
    int n = 0;
    for (int v = t; v < V && n < 8; v += T) own[n++] = v;
    int done = 0;
    long idle = 0;
    while (done < n) {
        bool progress = false;
        for (int i = 0; i < n; i++) {
            int v = own[i];
            if (v < 0) continue;
            int st = __hip_atomic_load(&resolved[v], __ATOMIC_RELAXED, __HIP_MEMORY_SCOPE_AGENT);
            if (st == 0) continue;
            // process v exactly once
            const int* row = neighs + (size_t)v * (size_t)K;
            unsigned long long kv = key[v];
            if (st == ST_CENTER) {
                for (int k = 0; k < K; k++) {
                    int w2 = row[k];
                    if (w2 < 0) continue;
                    if (kv > key[w2]) atomicMax(&best[w2], kv);  // key embeds id => absorber record
                }
                __threadfence();   // maxes visible before any of our decrements
            }
            for (int k = 0; k < K; k++) {
                int w2 = row[k];
                if (w2 < 0) continue;
                if (kv > key[w2]) {
                    if (atomicSub(&pred[w2], 1) == 1) {          // we resolved w2
                        __threadfence();                          // acquire all preds' maxes
                        unsigned long long b =
                            __hip_atomic_load(&best[w2], __ATOMIC_RELAXED, __HIP_MEMORY_SCOPE_AGENT);
                        __hip_atomic_store(&resolved[w2], b ? ST_ABSORBED : ST_CENTER,
                                           __ATOMIC_RELAXED, __HIP_MEMORY_SCOPE_AGENT);
                    }
                }
            }
            own[i] = -1;
            done++;
            progress = true;
        }
        if (done < n && !progress) {
            __builtin_amdgcn_s_sleep(2);
            if (++idle > 20000000L) break;   // safety net: never hang the bench
        }
    }
}

// ---------------- compact centers per segment ----------------
__global__ void k_compact(const unsigned long long* __restrict__ key,
                          const int* __restrict__ resolved,
                          const int* __restrict__ row_splits,
                          unsigned long long* __restrict__ segKeys,
                          int* __restrict__ segIds,
                          int* __restrict__ counters,
                          int V, int NSEG) {
    int v = blockIdx.x * blockDim.x + threadIdx.x;
    if (v >= V) return;
    if (resolved[v] != ST_CENTER) return;
    int s = 0;
    while (s + 1 < NSEG && v >= row_splits[s + 1]) s++;
    int p = atomicAdd(&counters[s], 1);
    int base = row_splits[s];
    segKeys[base + p] = key[v];
    segIds[base + p]  = v;
}

// ---------------- rs prefix (tiny) ----------------
__global__ void k_rs(const int* __restrict__ counters,
                     int* __restrict__ rsBase,
                     int* __restrict__ rs_out,
                     int NSEG) {
    if (blockIdx.x == 0 && threadIdx.x == 0) {
        int acc = 0;
        rs_out[0] = 0;
        for (int s = 0; s < NSEG; s++) {
            rsBase[s] = acc;
            acc += counters[s];
            rs_out[s + 1] = acc;
        }
    }
}

// ---------------- rank centers -> cid, sel ----------------
__global__ void k_rank(const unsigned long long* __restrict__ segKeys,
                       const int* __restrict__ segIds,
                       const int* __restrict__ counters,
                       const int* __restrict__ rsBase,
                       const int* __restrict__ row_splits,
                       int* __restrict__ cidOf,
                       int* __restrict__ sel_out,
                       int V, int NSEG) {
    int t = blockIdx.x * blockDim.x + threadIdx.x;
    if (t >= V) return;
    int s = 0;
    while (s + 1 < NSEG && t >= row_splits[s + 1]) s++;
    int base = row_splits[s];
    int j = t - base;
    int cnt = counters[s];
    if (j >= cnt) return;
    unsigned long long mk = segKeys[t];
    int r = 0;
    for (int i = 0; i < cnt; i++) r += (segKeys[base + i] > mk) ? 1 : 0;
    int cid = rsBase[s] + r;
    int v = segIds[t];
    cidOf[v] = cid;
    sel_out[cid] = v;
}

// ---------------- final cluster assignment ----------------
__global__ void k_assign(const int* __restrict__ resolved,
                         const unsigned long long* __restrict__ best,
                         const int* __restrict__ cidOf,
                         int* __restrict__ clus_out,
                         int V) {
    int v = blockIdx.x * blockDim.x + threadIdx.x;
    if (v >= V) return;
    int st = resolved[v];
    int c = 0;
    if (st == ST_CENTER) {
        c = cidOf[v];
    } else {
        unsigned long long b = best[v];
        if (b != 0ull) {
            uint32_t a = ~(uint32_t)(b & 0xFFFFFFFFull);   // absorber global index
            c = cidOf[a];
        }
    }
    clus_out[v] = c;
}

extern "C" void kernel_launch(void* const* d_in, const int* in_sizes, int n_in,
                              void* d_out, int out_size, void* d_ws, size_t ws_size,
                              hipStream_t stream) {
    const int*   neighs     = (const int*)d_in[0];
    const float* hier       = (const float*)d_in[1];
    const int*   row_splits = (const int*)d_in[2];

    const int V    = in_sizes[1];
    const int K    = in_sizes[0] / V;
    const int NSEG = in_sizes[2] - 1;
    const long E   = (long)V * (long)K;
    int kshift = -1;
    if ((K & (K - 1)) == 0) { kshift = 0; while ((1 << kshift) < K) kshift++; }

    int* out      = (int*)d_out;
    int* sel_out  = out;
    int* rs_out   = out + V;
    int* clus_out = out + V + NSEG + 1;

    // workspace layout (u64 arrays first for alignment): 40V + 256 bytes
    char* w = (char*)d_ws;
    unsigned long long* key     = (unsigned long long*)(w);
    unsigned long long* best    = (unsigned long long*)(w + (size_t)8 * V);
    unsigned long long* segKeys = (unsigned long long*)(w + (size_t)16 * V);
    int* pred     = (int*)(w + (size_t)24 * V);
    int* resolved = (int*)(w + (size_t)28 * V);
    int* cidOf    = (int*)(w + (size_t)32 * V);
    int* segIds   = (int*)(w + (size_t)36 * V);
    int* counters = (int*)(w + (size_t)40 * V);       // [0..15] segCount, [16..31] rsBase

    const int B  = 256;
    const int gV = (V + B - 1) / B;

    k_init<<<gV, B, 0, stream>>>(hier, key, best, pred, resolved, counters, sel_out, V);
    k_build<<<(int)((E + B - 1) / B), B, 0, stream>>>(neighs, key, pred, E, K, kshift);
    k_seed<<<gV, B, 0, stream>>>(pred, resolved, V);

    const int PB = 512;                 // 2 blocks/CU guaranteed co-resident
    const int T  = PB * B;
    k_propagate<<<PB, B, 0, stream>>>(neighs, key, best, pred, resolved, V, K, T);

    k_compact<<<gV, B, 0, stream>>>(key, resolved, row_splits, segKeys, segIds, counters, V, NSEG);
    k_rs<<<1, 64, 0, stream>>>(counters, counters + 16, rs_out, NSEG);
    k_rank<<<gV, B, 0, stream>>>(segKeys, segIds, counters, counters + 16, row_splits,
                                 cidOf, sel_out, V, NSEG);
    k_assign<<<gV, B, 0, stream>>>(resolved, best, cidOf, clus_out, V);
}

// Round 2
// 4314.318 us; speedup vs baseline: 3.1205x; 3.1205x over previous
//
#include <hip/hip_runtime.h>
#include <stdint.h>

// status codes
#define ST_UNK  0
#define ST_ABS  1   // decided absorbed (short-circuit: first center max)
#define ST_DONE 2   // decided via pred==0 (center iff best==0)

static __device__ __forceinline__ uint32_t f2key(float f) {
    uint32_t u = __float_as_uint(f);
    return (u & 0x80000000u) ? ~u : (u | 0x80000000u);
}

// ---------------- init ----------------
__global__ void k_init(const float* __restrict__ hier,
                       unsigned long long* __restrict__ key,
                       unsigned long long* __restrict__ best,
                       int* __restrict__ pred,
                       int* __restrict__ status,
                       int* __restrict__ counters,
                       int* __restrict__ sel_out,
                       int V) {
    int v = blockIdx.x * blockDim.x + threadIdx.x;
    if (v < 64) counters[v] = 0;
    if (v >= V) return;
    key[v]    = ((unsigned long long)f2key(hier[v]) << 32) | (unsigned long long)(~(uint32_t)v);
    best[v]   = 0ull;
    pred[v]   = 0;
    status[v] = ST_UNK;
    sel_out[v] = -1;
}

// ---------------- build in-degree of "absorption" DAG ----------------
__global__ void k_build(const int* __restrict__ neighs,
                        const unsigned long long* __restrict__ key,
                        int* __restrict__ pred,
                        long E, int K, int kshift) {
    long e = (long)blockIdx.x * blockDim.x + threadIdx.x;
    if (e >= E) return;
    int w = neighs[e];
    if (w < 0) return;
    int u = (kshift >= 0) ? (int)(e >> kshift) : (int)(e / K);
    if (key[u] > key[w]) atomicAdd(&pred[w], 1);   // u is a higher-priority pred of w
}

// ---------------- seed: no higher-priority pred => decided (center) ----------------
__global__ void k_seed(const int* __restrict__ pred, int* __restrict__ status, int V) {
    int v = blockIdx.x * blockDim.x + threadIdx.x;
    if (v >= V) return;
    if (pred[v] == 0) status[v] = ST_DONE;   // best==0 -> classified center by owners
}

// ---------------- propagation: wave-cooperative static ownership ----------------
// Each wave owns contiguous 64-vertex groups (coalesced status polls).
// A decided vertex is processed by all 64 lanes: lane k handles edge k.
// Decisions: ABS as soon as the first center maxes into best (old==0);
// DONE when pred hits 0 (center iff best==0 at that point — all in-neighbor
// centers' maxes precede their subs per the inter-phase fence).
__global__ __launch_bounds__(256, 4)
void k_propagate(const int* __restrict__ neighs,
                 const unsigned long long* __restrict__ key,
                 unsigned long long* __restrict__ best,
                 int* __restrict__ pred,
                 int* __restrict__ status,
                 int V, int K, int nwaves) {
    const int gtid = blockIdx.x * blockDim.x + threadIdx.x;
    const int wv   = gtid >> 6;
    const int lane = gtid & 63;
    const int G    = (V + 63) >> 6;

    int gbase[8];
    int ng = 0;
    for (int g = wv; g < G && ng < 8; g += nwaves) gbase[ng++] = g << 6;
    unsigned pend = 0;
    for (int i = 0; i < ng; i++) if (gbase[i] + lane < V) pend |= 1u << i;

    long sweeps = 0;
    while (!__all(pend == 0)) {
        bool found = false;
        for (int i = 0; i < ng; i++) {
            if (__all(((pend >> i) & 1u) == 0)) continue;
            int  v    = gbase[i] + lane;
            bool mine = (pend >> i) & 1u;
            int  st   = ST_UNK;
            if (mine)
                st = __hip_atomic_load(&status[v], __ATOMIC_RELAXED, __HIP_MEMORY_SCOPE_AGENT);
            uint64_t mrdy = __ballot(mine && st != ST_UNK);
            if (!mrdy) continue;
            found = true;
            __threadfence();   // acquire: order the best-reads below after status observation

            bool cen = false;
            if (mine && st == ST_DONE) {
                unsigned long long b =
                    __hip_atomic_load(&best[v], __ATOMIC_RELAXED, __HIP_MEMORY_SCOPE_AGENT);
                cen = (b == 0ull);
            }
            uint64_t mcen = __ballot(cen);

            // phase A: centers broadcast their key into lower-key neighbours
            uint64_t m = mcen;
            while (m) {
                int l = __ffsll((unsigned long long)m) - 1; m &= m - 1;
                int vv = gbase[i] + l;
                unsigned long long kv = key[vv];
                const int* row = neighs + (size_t)vv * (size_t)K;
                for (int k = lane; k < K; k += 64) {
                    int w = row[k];
                    if (w >= 0 && kv > key[w]) {
                        unsigned long long old = atomicMax(&best[w], kv);
                        if (old == 0ull)   // first center to reach w -> absorbed, decided now
                            __hip_atomic_store(&status[w], ST_ABS,
                                               __ATOMIC_RELAXED, __HIP_MEMORY_SCOPE_AGENT);
                    }
                }
            }
            if (mcen) __threadfence();   // all our maxes land before any of our subs

            // phase B: every decided vertex releases its lower-key out-edges
            m = mrdy;
            while (m) {
                int l = __ffsll((unsigned long long)m) - 1; m &= m - 1;
                int vv = gbase[i] + l;
                unsigned long long kv = key[vv];
                const int* row = neighs + (size_t)vv * (size_t)K;
                for (int k = lane; k < K; k += 64) {
                    int w = row[k];
                    if (w >= 0 && kv > key[w]) {
                        if (atomicSub(&pred[w], 1) == 1)
                            __hip_atomic_store(&status[w], ST_DONE,
                                               __ATOMIC_RELEASE, __HIP_MEMORY_SCOPE_AGENT);
                    }
                }
            }
            if (mine && st != ST_UNK) pend &= ~(1u << i);
        }
        if (!found) {
            __builtin_amdgcn_s_sleep(8);
            if (++sweeps > 300000) break;   // safety net: never hang the bench
        }
    }
}

// ---------------- compact centers per segment ----------------
__global__ void k_compact(const unsigned long long* __restrict__ key,
                          const unsigned long long* __restrict__ best,
                          const int* __restrict__ row_splits,
                          unsigned long long* __restrict__ segKeys,
                          int* __restrict__ segIds,
                          int* __restrict__ counters,
                          int V, int NSEG) {
    int v = blockIdx.x * blockDim.x + threadIdx.x;
    if (v >= V) return;
    if (best[v] != 0ull) return;            // center <=> never absorbed
    int s = 0;
    while (s + 1 < NSEG && v >= row_splits[s + 1]) s++;
    int p = atomicAdd(&counters[s], 1);
    int base = row_splits[s];
    segKeys[base + p] = key[v];
    segIds[base + p]  = v;
}

// ---------------- rs prefix (tiny) ----------------
__global__ void k_rs(const int* __restrict__ counters,
                     int* __restrict__ rsBase,
                     int* __restrict__ rs_out,
                     int NSEG) {
    if (blockIdx.x == 0 && threadIdx.x == 0) {
        int acc = 0;
        rs_out[0] = 0;
        for (int s = 0; s < NSEG; s++) {
            rsBase[s] = acc;
            acc += counters[s];
            rs_out[s + 1] = acc;
        }
    }
}

// ---------------- rank centers -> cid, sel ----------------
__global__ void k_rank(const unsigned long long* __restrict__ segKeys,
                       const int* __restrict__ segIds,
                       const int* __restrict__ counters,
                       const int* __restrict__ rsBase,
                       const int* __restrict__ row_splits,
                       int* __restrict__ cidOf,
                       int* __restrict__ sel_out,
                       int V, int NSEG) {
    int t = blockIdx.x * blockDim.x + threadIdx.x;
    if (t >= V) return;
    int s = 0;
    while (s + 1 < NSEG && t >= row_splits[s + 1]) s++;
    int base = row_splits[s];
    int j = t - base;
    int cnt = counters[s];
    if (j >= cnt) return;
    unsigned long long mk = segKeys[t];
    int r = 0;
    for (int i = 0; i < cnt; i++) r += (segKeys[base + i] > mk) ? 1 : 0;
    int cid = rsBase[s] + r;
    int v = segIds[t];
    cidOf[v] = cid;
    sel_out[cid] = v;
}

// ---------------- final cluster assignment ----------------
__global__ void k_assign(const unsigned long long* __restrict__ best,
                         const int* __restrict__ cidOf,
                         int* __restrict__ clus_out,
                         int V) {
    int v = blockIdx.x * blockDim.x + threadIdx.x;
    if (v >= V) return;
    unsigned long long b = best[v];
    int c;
    if (b == 0ull) {
        c = cidOf[v];                              // center
    } else {
        uint32_t a = ~(uint32_t)(b & 0xFFFFFFFFull);   // absorber global index
        c = cidOf[a];
    }
    clus_out[v] = c;
}

extern "C" void kernel_launch(void* const* d_in, const int* in_sizes, int n_in,
                              void* d_out, int out_size, void* d_ws, size_t ws_size,
                              hipStream_t stream) {
    const int*   neighs     = (const int*)d_in[0];
    const float* hier       = (const float*)d_in[1];
    const int*   row_splits = (const int*)d_in[2];

    const int V    = in_sizes[1];
    const int K    = in_sizes[0] / V;
    const int NSEG = in_sizes[2] - 1;
    const long E   = (long)V * (long)K;
    int kshift = -1;
    if ((K & (K - 1)) == 0) { kshift = 0; while ((1 << kshift) < K) kshift++; }

    int* out      = (int*)d_out;
    int* sel_out  = out;
    int* rs_out   = out + V;
    int* clus_out = out + V + NSEG + 1;

    // workspace layout (u64 arrays first for alignment): 40V + 256 bytes
    char* w = (char*)d_ws;
    unsigned long long* key     = (unsigned long long*)(w);
    unsigned long long* best    = (unsigned long long*)(w + (size_t)8 * V);
    unsigned long long* segKeys = (unsigned long long*)(w + (size_t)16 * V);
    int* pred     = (int*)(w + (size_t)24 * V);
    int* status   = (int*)(w + (size_t)28 * V);
    int* cidOf    = (int*)(w + (size_t)32 * V);
    int* segIds   = (int*)(w + (size_t)36 * V);
    int* counters = (int*)(w + (size_t)40 * V);       // [0..15] segCount, [16..31] rsBase

    const int B  = 256;
    const int gV = (V + B - 1) / B;

    k_init<<<gV, B, 0, stream>>>(hier, key, best, pred, status, counters, sel_out, V);
    k_build<<<(int)((E + B - 1) / B), B, 0, stream>>>(neighs, key, pred, E, K, kshift);
    k_seed<<<gV, B, 0, stream>>>(pred, status, V);

    const int PB = 1024;                 // 4 blocks/CU co-resident (48 VGPR, 0 LDS)
    const int NW = PB * B / 64;          // 4096 waves
    k_propagate<<<PB, B, 0, stream>>>(neighs, key, best, pred, status, V, K, NW);

    k_compact<<<gV, B, 0, stream>>>(key, best, row_splits, segKeys, segIds, counters, V, NSEG);
    k_rs<<<1, 64, 0, stream>>>(counters, counters + 16, rs_out, NSEG);
    k_rank<<<gV, B, 0, stream>>>(segKeys, segIds, counters, counters + 16, row_splits,
                                 cidOf, sel_out, V, NSEG);
    k_assign<<<gV, B, 0, stream>>>(best, cidOf, clus_out, V);
}